// Round 1
// 133.237 us; speedup vs baseline: 1.1456x; 1.1456x over previous
//
#include <hip/hip_runtime.h>
#include <hip/hip_bf16.h>

#define NRAYS 8192
#define SAMP  128
#define DVD   27
#define NFEAT 15

typedef float  f32x4  __attribute__((ext_vector_type(4)));
typedef short  short8 __attribute__((ext_vector_type(8)));
typedef unsigned int u32x2 __attribute__((ext_vector_type(2)));

// fast fp32 -> bf16 (round-half-up): store HIGH short of (bits + 0x8000)
static __device__ __forceinline__ void stbf(short* p, float x) {
    union { unsigned u; struct { short lo, hi; } s; } v;
    v.u = __float_as_uint(x) + 0x8000u;
    *p = v.s.hi;
}
static __device__ __forceinline__ float bf2f(short s) {
    return __uint_as_float(((unsigned)(unsigned short)s) << 16);
}
// pack two fp32 -> dword of two bf16 (lo -> low half), HW RNE convert
static __device__ __forceinline__ unsigned pk2bf(float lo, float hi) {
    unsigned r;
    asm("v_cvt_pk_bf16_f32 %0, %1, %2" : "=v"(r) : "v"(lo), "v"(hi));
    return r;
}
static __device__ __forceinline__ float sin_fast(float x) {
    float r = x * 0.15915494309189535f;
    r = r - floorf(r);
    return __builtin_amdgcn_sinf(r);
}
static __device__ __forceinline__ float cos_fast(float x) {
    float r = x * 0.15915494309189535f;
    r = r - floorf(r);
    return __builtin_amdgcn_cosf(r);
}

// LDS layout (overlay) — same footprint as R14 (32208 B, 5 blk/CU):
//   staging (pre-b2): sW1t@0 [64*72]s 9216B, sW2t@9216 [16*72]s 2304B,
//                     sV1t@11520 [64*32]s 4096B, sV2t@15616 [3*72]s 432B
//   working (post-b2): sE@0 [4][32*72]s 18432B, sG@18432 [4][32*32]s 8192B
//   persistent: sOm@26624 [4][128]f 2048B, sRgb@28672 [4][384]s 3072B,
//               sVde@31744 [4][28]f 448B, sRed@32192 [4]f 16B -> 32208 B
// E k-layout (NEW): band b at k=6b..6b+5 [sx sy sz cx cy cz], xyz at k=60..62,
//   k=63 == 1.0 (bias column; sW1t row 63 = b1).  W1 staging remapped to match.
// G k-layout: features at k=0..14, k=15 == 1.0 (bias col; sV1t row 15 = c1),
//   k=16..31 zero.
#define SMEM_BYTES 32208

__global__ void __launch_bounds__(256)
march_kernel(const float* __restrict__ orig,
             const float* __restrict__ dirs,
             const float* __restrict__ tmin,
             const float* __restrict__ tmax,
             const float* __restrict__ W1,
             const float* __restrict__ b1,
             const float* __restrict__ W2,
             const float* __restrict__ b2,
             const float* __restrict__ V1,
             const float* __restrict__ c1,
             const float* __restrict__ V2,
             const float* __restrict__ c2,
             float* __restrict__ out) {
    __shared__ __align__(16) char smem[SMEM_BYTES];
    short* const sW1t = (short*)(smem);            // [n*72 + newk]
    short* const sW2t = (short*)(smem + 9216);     // [n*72 + k]
    short* const sV1t = (short*)(smem + 11520);    // [n*32 + k]
    short* const sV2t = (short*)(smem + 15616);    // [n*72 + k], n<3
    short* const sEa  = (short*)(smem);            // [wave][32*72]
    short* const sGa  = (short*)(smem + 18432);    // [wave][32*32]
    float* const sOm  = (float*)(smem + 26624);    // [wave][128]
    short* const sRgb = (short*)(smem + 28672);    // [wave][384]
    float* const sVde = (float*)(smem + 31744);    // [wave][28]
    float* const sRed = (float*)(smem + 32192);    // [4]

    const int tid  = threadIdx.x;
    const int lane = tid & 63;
    const int wave = tid >> 6;
    const int ray  = blockIdx.x * 4 + wave;

    // ---- block-redundant dt partial: sum(tmax - tmin) ----
    {
        const float4* tm0 = (const float4*)tmin;
        const float4* tm1 = (const float4*)tmax;
        float s = 0.0f;
        #pragma unroll
        for (int it = 0; it < 8; it++) {
            const int i = tid + it * 256;
            const float4 a = tm1[i], b = tm0[i];
            s += (a.x - b.x) + (a.y - b.y) + (a.z - b.z) + (a.w - b.w);
        }
        #pragma unroll
        for (int off = 32; off > 0; off >>= 1)
            s += __shfl_xor(s, off, 64);
        if (lane == 0) sRed[wave] = s;
    }

    // ---- cooperative weight staging (coalesced global reads) ----
    for (int i = tid; i < 63 * 64; i += 256) {   // W1 [63][64], k remapped
        const int k = i >> 6, n = i & 63;
        const int nk = (k < 3) ? (60 + k) : (k - 3);
        stbf(&sW1t[n * 72 + nk], W1[i]);
    }
    for (int i = tid; i < 64; i += 256)          // bias column (k=63) = b1
        stbf(&sW1t[i * 72 + 63], b1[i]);
    for (int i = tid; i < 64 * 16; i += 256) {   // W2 [64][16]
        const int k = i >> 4, n = i & 15;
        stbf(&sW2t[n * 72 + k], W2[i]);
    }
    for (int i = tid; i < 15 * 64; i += 256) {   // V1 [15][64] (feature rows)
        const int k = i >> 6, n = i & 63;
        stbf(&sV1t[n * 32 + k], V1[i]);
    }
    for (int i = tid; i < 64; i += 256)          // bias column (k=15) = c1
        stbf(&sV1t[i * 32 + 15], c1[i]);
    for (int i = tid; i < 64 * 16; i += 256) {   // V1 pad k=16..31
        const int n = i >> 4, k = 16 + (i & 15);
        sV1t[n * 32 + k] = 0;
    }
    for (int i = tid; i < 192; i += 256) {       // V2 [64][3]
        const int k = i / 3, n = i - 3 * k;
        stbf(&sV2t[n * 72 + k], V2[i]);
    }

    // ---- per-ray scalars ----
    const float ox = orig[ray * 3 + 0];
    const float oy = orig[ray * 3 + 1];
    const float oz = orig[ray * 3 + 2];
    const float dx = dirs[ray * 3 + 0];
    const float dy = dirs[ray * 3 + 1];
    const float dz = dirs[ray * 3 + 2];
    const float t0v = tmin[ray];
    const float trange = tmax[ray] - t0v;

    // ---- view-dir encoding (fp32) -> sVde (per-wave) ----
    {
        const float nrm = sqrtf(dx * dx + dy * dy + dz * dz);
        const float inv = 1.0f / (nrm + 1e-8f);
        const float vx = dx * inv, vy = dy * inv, vz = dz * inv;
        if (lane < DVD) {
            float val;
            if (lane < 3) {
                val = (lane == 0) ? vx : ((lane == 1) ? vy : vz);
            } else {
                const int q = lane - 3;
                const int b = q / 6;
                const int r = q - 6 * b;
                const bool isSin = (r < 3);
                const int d = isSin ? r : (r - 3);
                const float comp = (d == 0) ? vx : ((d == 1) ? vy : vz);
                const float a = (float)(1 << b) * comp;
                val = isSin ? sin_fast(a) : cos_fast(a);
            }
            sVde[wave * 28 + lane] = val;
        }
    }
    __syncthreads();   // barrier 1: staging + dt reduce complete

    const float dtv = (sRed[0] + sRed[1] + sRed[2] + sRed[3]) *
                      (1.0f / ((float)NRAYS * (float)SAMP));

    const int nfr  = lane & 15;   // n (or m) within a 16-tile
    const int quad = lane >> 4;

    // ---- build B-fragments from LDS staging (ds_read_b128) ----
    // N-permutation: fragment tile nt at lane nfr holds GLOBAL column 4*nfr+nt
    // (so a lane's 4 output values per row are consecutive -> b64 packed store).
    short8 w1f[4][2], w2f[2], v1f[4], v2f[2];
    #pragma unroll
    for (int nt = 0; nt < 4; nt++)
        #pragma unroll
        for (int kt = 0; kt < 2; kt++)
            w1f[nt][kt] = *(const short8*)&sW1t[(4 * nfr + nt) * 72 + quad * 8 + kt * 32];
    #pragma unroll
    for (int kt = 0; kt < 2; kt++)
        w2f[kt] = *(const short8*)&sW2t[nfr * 72 + quad * 8 + kt * 32];
    #pragma unroll
    for (int nt = 0; nt < 4; nt++)
        v1f[nt] = *(const short8*)&sV1t[(4 * nfr + nt) * 32 + quad * 8];
    #pragma unroll
    for (int kt = 0; kt < 2; kt++) {
        if (nfr < 3)
            v2f[kt] = *(const short8*)&sV2t[nfr * 72 + quad * 8 + kt * 32];
        else
            v2f[kt] = (short8){0, 0, 0, 0, 0, 0, 0, 0};
    }

    // ---- remaining biases (b1/c1 folded into GEMMs via constant-1 columns) ----
    const float bb2 = b2[nfr];
    const float bc2 = (nfr < 3) ? c2[nfr] : 0.0f;

    // ---- gvde[nt] = sum_q vde[q] * V1[15+q][4*nfr+nt] (fp32, per ray) ----
    float gv[4] = {0.0f, 0.0f, 0.0f, 0.0f};
    #pragma unroll 1
    for (int q = 0; q < DVD; q++) {
        const float e = sVde[wave * 28 + q];
        const f32x4 vv = *(const f32x4*)&V1[(NFEAT + q) * 64 + 4 * nfr];
        gv[0] += e * vv.x; gv[1] += e * vv.y;
        gv[2] += e * vv.z; gv[3] += e * vv.w;
    }
    __syncthreads();   // barrier 2: fragment reads done before sE overwrite

    short* const myE = sEa + wave * (32 * 72);
    short* const myG = sGa + wave * (32 * 32);
    // zero myG (A-side pad must be finite; LDS is undefined at launch)
    {
        int* gz = (int*)myG;
        for (int i = lane; i < 32 * 16; i += 64) gz[i] = 0;
    }
    if (lane < 32) myG[lane * 32 + 15] = (short)0x3F80;  // bias column = 1.0

    const int sl   = lane >> 1;   // local sample 0..31 (enc phase)
    const int half = lane & 1;
    // chain seed frequency: half0 starts at band 0 (f=1), half1 at band 5 (f=32)
    const float fmul = half ? 5.0929581789406507f      // 32 / (2*pi)
                            : 0.15915494309189535f;    //  1 / (2*pi)

    #pragma unroll 1
    for (int qq = 0; qq < 4; qq++) {
        // --- positional encodings for 32 samples (2 lanes/sample, UNIFORM) ---
        // Each lane: one hw sincos per component, then 4 double-angle steps.
        {
            const int s = qq * 32 + sl;
            const float t = t0v + (float)s * (1.0f / 127.0f) * trange;
            const float px = ox + dx * t, py = oy + dy * t, pz = oz + dz * t;
            unsigned* Edw = (unsigned*)&myE[sl * 72];
            unsigned* Eh  = Edw + 15 * half;   // half0: dw 0..14, half1: 15..29
            float rx = px * fmul; rx -= floorf(rx);
            float ry = py * fmul; ry -= floorf(ry);
            float rz = pz * fmul; rz -= floorf(rz);
            float sx = __builtin_amdgcn_sinf(rx), cx = __builtin_amdgcn_cosf(rx);
            float sy = __builtin_amdgcn_sinf(ry), cy = __builtin_amdgcn_cosf(ry);
            float sz = __builtin_amdgcn_sinf(rz), cz = __builtin_amdgcn_cosf(rz);
            #pragma unroll
            for (int j = 0; j < 5; j++) {
                Eh[3 * j + 0] = pk2bf(sx, sy);
                Eh[3 * j + 1] = pk2bf(sz, cx);
                Eh[3 * j + 2] = pk2bf(cy, cz);
                if (j < 4) {   // double-angle: s'=2sc, c'=1-2s^2
                    const float tx = sx + sx, ty = sy + sy, tz = sz + sz;
                    const float nsx = tx * cx, nsy = ty * cy, nsz = tz * cz;
                    cx = __builtin_fmaf(-tx, sx, 1.0f);
                    cy = __builtin_fmaf(-ty, sy, 1.0f);
                    cz = __builtin_fmaf(-tz, sz, 1.0f);
                    sx = nsx; sy = nsy; sz = nsz;
                }
            }
            if (half == 0) {   // xyz at k=60..62, bias-1.0 at k=63
                u32x2 xyz;
                xyz.x = pk2bf(px, py);
                xyz.y = pk2bf(pz, 1.0f);
                *(u32x2*)(Edw + 30) = xyz;
            }
        }
        // --- layer 1: h = relu(E @ W1 + b1)   (b1 folded via k=63 col) ---
        f32x4 acc1[2][4];
        #pragma unroll
        for (int mt = 0; mt < 2; mt++)
            #pragma unroll
            for (int nt = 0; nt < 4; nt++)
                acc1[mt][nt] = (f32x4){0.0f, 0.0f, 0.0f, 0.0f};
        {
            short8 af[2][2];
            #pragma unroll
            for (int mt = 0; mt < 2; mt++)
                #pragma unroll
                for (int kt = 0; kt < 2; kt++)
                    af[mt][kt] = *(const short8*)&myE[(nfr + 16 * mt) * 72 + quad * 8 + kt * 32];
            #pragma unroll
            for (int mt = 0; mt < 2; mt++)
                #pragma unroll
                for (int nt = 0; nt < 4; nt++)
                    #pragma unroll
                    for (int kt = 0; kt < 2; kt++)
                        acc1[mt][nt] = __builtin_amdgcn_mfma_f32_16x16x32_bf16(
                            af[mt][kt], w1f[nt][kt], acc1[mt][nt], 0, 0, 0);
        }
        // packed epilogue: lane's 4 cols are global n = 4*nfr..4*nfr+3
        #pragma unroll
        for (int mt = 0; mt < 2; mt++)
            #pragma unroll
            for (int r = 0; r < 4; r++) {
                const int m = 4 * quad + r + 16 * mt;
                u32x2 hp;
                hp.x = pk2bf(fmaxf(acc1[mt][0][r], 0.0f),
                             fmaxf(acc1[mt][1][r], 0.0f));
                hp.y = pk2bf(fmaxf(acc1[mt][2][r], 0.0f),
                             fmaxf(acc1[mt][3][r], 0.0f));
                *(u32x2*)&myE[m * 72 + 4 * nfr] = hp;
            }
        // --- W2: O = h @ W2 + b2 ---
        f32x4 acc2[2];
        acc2[0] = (f32x4){0.0f, 0.0f, 0.0f, 0.0f};
        acc2[1] = (f32x4){0.0f, 0.0f, 0.0f, 0.0f};
        {
            short8 ah[2][2];
            #pragma unroll
            for (int mt = 0; mt < 2; mt++)
                #pragma unroll
                for (int kt = 0; kt < 2; kt++)
                    ah[mt][kt] = *(const short8*)&myE[(nfr + 16 * mt) * 72 + quad * 8 + kt * 32];
            #pragma unroll
            for (int mt = 0; mt < 2; mt++)
                #pragma unroll
                for (int kt = 0; kt < 2; kt++)
                    acc2[mt] = __builtin_amdgcn_mfma_f32_16x16x32_bf16(
                        ah[mt][kt], w2f[kt], acc2[mt], 0, 0, 0);
        }
        if (nfr == 0) {
            #pragma unroll
            for (int mt = 0; mt < 2; mt++)
                #pragma unroll
                for (int r = 0; r < 4; r++) {
                    const int m = 4 * quad + r + 16 * mt;
                    const float sg = fmaxf(acc2[mt][r] + bb2, 0.0f);
                    sOm[wave * 128 + qq * 32 + m] = __expf(-sg * dtv);
                }
        } else {
            #pragma unroll
            for (int mt = 0; mt < 2; mt++)
                #pragma unroll
                for (int r = 0; r < 4; r++) {
                    const int m = 4 * quad + r + 16 * mt;
                    stbf(&myG[m * 32 + (nfr - 1)], acc2[mt][r] + bb2);
                }
        }
        // --- V1: g = relu(G_in @ V1 + c1 + gvde)  (c1 folded via k=15 col) ---
        f32x4 acc3[2][4];
        #pragma unroll
        for (int mt = 0; mt < 2; mt++)
            #pragma unroll
            for (int nt = 0; nt < 4; nt++)
                acc3[mt][nt] = (f32x4){0.0f, 0.0f, 0.0f, 0.0f};
        {
            short8 ag[2];
            #pragma unroll
            for (int mt = 0; mt < 2; mt++)
                ag[mt] = *(const short8*)&myG[(nfr + 16 * mt) * 32 + quad * 8];
            #pragma unroll
            for (int mt = 0; mt < 2; mt++)
                #pragma unroll
                for (int nt = 0; nt < 4; nt++)
                    acc3[mt][nt] = __builtin_amdgcn_mfma_f32_16x16x32_bf16(
                        ag[mt], v1f[nt], acc3[mt][nt], 0, 0, 0);
        }
        #pragma unroll
        for (int mt = 0; mt < 2; mt++)
            #pragma unroll
            for (int r = 0; r < 4; r++) {
                const int m = 4 * quad + r + 16 * mt;
                u32x2 gp;
                gp.x = pk2bf(fmaxf(acc3[mt][0][r] + gv[0], 0.0f),
                             fmaxf(acc3[mt][1][r] + gv[1], 0.0f));
                gp.y = pk2bf(fmaxf(acc3[mt][2][r] + gv[2], 0.0f),
                             fmaxf(acc3[mt][3][r] + gv[3], 0.0f));
                *(u32x2*)&myE[m * 72 + 4 * nfr] = gp;
            }
        // --- V2: rgb = sigmoid(g @ V2 + c2) ---
        f32x4 acc4[2];
        acc4[0] = (f32x4){0.0f, 0.0f, 0.0f, 0.0f};
        acc4[1] = (f32x4){0.0f, 0.0f, 0.0f, 0.0f};
        {
            short8 agg[2][2];
            #pragma unroll
            for (int mt = 0; mt < 2; mt++)
                #pragma unroll
                for (int kt = 0; kt < 2; kt++)
                    agg[mt][kt] = *(const short8*)&myE[(nfr + 16 * mt) * 72 + quad * 8 + kt * 32];
            #pragma unroll
            for (int mt = 0; mt < 2; mt++)
                #pragma unroll
                for (int kt = 0; kt < 2; kt++)
                    acc4[mt] = __builtin_amdgcn_mfma_f32_16x16x32_bf16(
                        agg[mt][kt], v2f[kt], acc4[mt], 0, 0, 0);
        }
        if (nfr < 3) {
            #pragma unroll
            for (int mt = 0; mt < 2; mt++)
                #pragma unroll
                for (int r = 0; r < 4; r++) {
                    const int m = 4 * quad + r + 16 * mt;
                    const float val = acc4[mt][r] + bc2;
                    stbf(&sRgb[wave * 384 + (qq * 32 + m) * 3 + nfr],
                         1.0f / (1.0f + __expf(-val)));
                }
        }
    }

    // ---- exclusive multiplicative scan + weighted reduce (per wave) ----
    const float om0 = sOm[wave * 128 + 2 * lane];
    const float om1 = sOm[wave * 128 + 2 * lane + 1];
    const float al0 = 1.0f - om0;
    const float al1 = 1.0f - om1;

    float inc = om0 * om1;
    #pragma unroll
    for (int off = 1; off < 64; off <<= 1) {
        const float q = __shfl_up(inc, off, 64);
        if (lane >= off) inc *= q;
    }
    float Texc = __shfl_up(inc, 1, 64);
    if (lane == 0) Texc = 1.0f;

    const float T0 = Texc;
    const float T1 = Texc * om0;
    const float a0 = (T0 > 1e-4f) ? 1.0f : 0.0f;
    const float a1 = (T1 > 1e-4f) ? 1.0f : 0.0f;
    const float w0 = T0 * al0 * a0;
    const float w1 = T1 * al1 * a1;

    float cr = w0 * bf2f(sRgb[wave * 384 + (2 * lane) * 3 + 0]) +
               w1 * bf2f(sRgb[wave * 384 + (2 * lane + 1) * 3 + 0]);
    float cg = w0 * bf2f(sRgb[wave * 384 + (2 * lane) * 3 + 1]) +
               w1 * bf2f(sRgb[wave * 384 + (2 * lane + 1) * 3 + 1]);
    float cb = w0 * bf2f(sRgb[wave * 384 + (2 * lane) * 3 + 2]) +
               w1 * bf2f(sRgb[wave * 384 + (2 * lane + 1) * 3 + 2]);
    float tp = (a0 > 0.0f ? om0 : 1.0f) * (a1 > 0.0f ? om1 : 1.0f);

    #pragma unroll
    for (int off = 32; off > 0; off >>= 1) {
        cr += __shfl_xor(cr, off, 64);
        cg += __shfl_xor(cg, off, 64);
        cb += __shfl_xor(cb, off, 64);
        tp *= __shfl_xor(tp, off, 64);
    }

    if (lane == 0) {
        out[ray * 3 + 0] = cr;
        out[ray * 3 + 1] = cg;
        out[ray * 3 + 2] = cb;
        out[NRAYS * 3 + ray] = tp;
    }
}

extern "C" void kernel_launch(void* const* d_in, const int* in_sizes, int n_in,
                              void* d_out, int out_size, void* d_ws, size_t ws_size,
                              hipStream_t stream) {
    const float* orig = (const float*)d_in[0];
    const float* dirs = (const float*)d_in[1];
    const float* tmin = (const float*)d_in[2];
    const float* tmax = (const float*)d_in[3];
    const float* W1   = (const float*)d_in[4];
    const float* b1   = (const float*)d_in[5];
    const float* W2   = (const float*)d_in[6];
    const float* b2   = (const float*)d_in[7];
    const float* V1   = (const float*)d_in[8];
    const float* c1   = (const float*)d_in[9];
    const float* V2   = (const float*)d_in[10];
    const float* c2   = (const float*)d_in[11];

    march_kernel<<<NRAYS / 4, 256, 0, stream>>>(orig, dirs, tmin, tmax,
                                                W1, b1, W2, b2, V1, c1, V2, c2,
                                                (float*)d_out);
}